// Round 15
// baseline (88.705 us; speedup 1.0000x reference)
//
#include <hip/hip_runtime.h>

typedef __attribute__((ext_vector_type(4))) float f32x4;
typedef __attribute__((ext_vector_type(8))) __bf16 bf16x8;
typedef __attribute__((ext_vector_type(4))) unsigned short us4;
typedef __attribute__((ext_vector_type(8))) unsigned short us8;

#define DEVI static __device__ __forceinline__

constexpr int T_ = 2048, E_ = 1024, H_ = 16, D_ = 64;
#define QSCALE (0.125f * 1.44269504088896f)  /* 1/sqrt(D) * log2(e) */

DEVI unsigned short f2b(float f) {
  union { __bf16 b; unsigned short u; } c; c.b = (__bf16)f; return c.u;
}

DEVI unsigned pkw(float a, float b) {  // pack 2 f32 -> 2 bf16 in one u32
  union { __bf16 h[2]; unsigned u; } c;
  c.h[0] = (__bf16)a; c.h[1] = (__bf16)b; return c.u;
}

#if __has_builtin(__builtin_amdgcn_exp2f)
DEVI float fexp2(float x) { return __builtin_amdgcn_exp2f(x); }
#else
DEVI float fexp2(float x) { return __expf(x * 0.69314718056f); }
#endif

DEVI f32x4 mfma16(bf16x8 a, bf16x8 b, f32x4 c) {
  return __builtin_amdgcn_mfma_f32_16x16x32_bf16(a, b, c, 0, 0, 0);
}

// async global->LDS 16B/lane: per-lane global src, wave-uniform LDS base (+lane*16)
DEVI void gl16(const void* g, void* l) {
  __builtin_amdgcn_global_load_lds(
      (const __attribute__((address_space(1))) unsigned int*)g,
      (__attribute__((address_space(3))) unsigned int*)l, 16, 0, 0);
}

// ---------------- single weight-conversion kernel (run once, first) ----------------
__launch_bounds__(256)
__global__ void cvt_kernel(const float* __restrict__ Wq,
                           const float* __restrict__ Wk,
                           const float* __restrict__ Wv,
                           const float* __restrict__ Wp,
                           unsigned short* __restrict__ wqb,
                           unsigned short* __restrict__ wkb,
                           unsigned short* __restrict__ wvb,
                           unsigned short* __restrict__ wpb)
{
  int blk = blockIdx.x;
  const float* src; unsigned short* dst; float s = 1.0f;
  if (blk < 64)       { src = Wq; dst = wqb; s = QSCALE; }
  else if (blk < 128) { src = Wk; dst = wkb; blk -= 64; }
  else if (blk < 192) { src = Wv; dst = wvb; blk -= 128; }
  else                { src = Wp; dst = wpb; blk -= 192; }
  int i = blk * 256 + threadIdx.x;
  float4 v = *(const float4*)(src + (size_t)i * 4);
  us4 o; o[0] = f2b(v.x * s); o[1] = f2b(v.y * s); o[2] = f2b(v.z * s); o[3] = f2b(v.w * s);
  *(us4*)(dst + (size_t)i * 4) = o;
}

// ---------------- QKV projection: writes K/V in FLASH-NATIVE layout ----------------
// kb2/vt2 hold, per (bh, 64-row s-block), the exact 8KB LDS byte image flash wants:
//  K: row rho64(s), granule (d>>3) ^ (rho&7)  (rho-permute + XOR swizzle)
//  V: row d, physical granule sigma-composed ({own first-4, partner(^2) second-4})
// grid: (B*H=32, T/128=16), block 256; LDS = Xl only
__launch_bounds__(256)
__global__ void qkv_kernel(const float* __restrict__ x,
                           const unsigned short* __restrict__ wqb,
                           const float* __restrict__ bq,
                           const unsigned short* __restrict__ wkb,
                           const float* __restrict__ bk,
                           const unsigned short* __restrict__ wvb,
                           const float* __restrict__ bv,
                           unsigned short* __restrict__ qo,
                           unsigned short* __restrict__ kb2,
                           unsigned short* __restrict__ vt2)
{
  const int bh = blockIdx.x;
  const int b  = bh >> 4;
  const int h  = bh & (H_ - 1);
  const int t0 = blockIdx.y * 128;
  __shared__ unsigned short Xl[128][72];
  const int tid = threadIdx.x;

  #pragma unroll
  for (int p = 0; p < 8; ++p) {
    int idx = p * 256 + tid;
    int row = idx >> 4, c4 = idx & 15;
    float4 v = *(const float4*)(x + ((size_t)(b * T_ + t0 + row)) * E_ + h * 64 + c4 * 4);
    us4 o; o[0] = f2b(v.x); o[1] = f2b(v.y); o[2] = f2b(v.z); o[3] = f2b(v.w);
    *(us4*)&Xl[row][c4 * 4] = o;
  }
  __syncthreads();

  const int w = tid >> 6, lane = tid & 63, lo = lane & 15, g = lane >> 4;
  const int tl0 = w * 32;

  bf16x8 xb[2][2];
  #pragma unroll
  for (int tt = 0; tt < 2; ++tt)
    #pragma unroll
    for (int kd = 0; kd < 2; ++kd)
      xb[tt][kd] = *(const bf16x8*)&Xl[tl0 + tt * 16 + lo][kd * 32 + g * 8];

  // Q and K: C = W * X^T  (o x t)
  #pragma unroll
  for (int tsel = 0; tsel < 2; ++tsel) {
    const float* bias = tsel ? bk : bq;
    const unsigned short* wsrc = (tsel ? wkb : wqb) + (size_t)h * 4096;
    const float bs = tsel ? 1.0f : QSCALE;
    #pragma unroll
    for (int ot = 0; ot < 4; ++ot) {
      bf16x8 a0 = *(const bf16x8*)(wsrc + (ot * 16 + lo) * 64 + g * 8);
      bf16x8 a1 = *(const bf16x8*)(wsrc + (ot * 16 + lo) * 64 + 32 + g * 8);
      float4 bv4 = *(const float4*)(bias + h * 64 + ot * 16 + g * 4);
      float bb[4] = {bv4.x * bs, bv4.y * bs, bv4.z * bs, bv4.w * bs};
      #pragma unroll
      for (int tt = 0; tt < 2; ++tt) {
        f32x4 acc = {0.f, 0.f, 0.f, 0.f};
        acc = mfma16(a0, xb[tt][0], acc);
        acc = mfma16(a1, xb[tt][1], acc);
        int tg = t0 + tl0 + tt * 16 + lo;
        us4 pk;
        #pragma unroll
        for (int r = 0; r < 4; ++r) pk[r] = f2b(acc[r] + bb[r]);
        if (tsel == 0) {
          *(us4*)(qo + ((size_t)(bh * T_ + tg)) * 64 + ot * 16 + g * 4) = pk;
        } else {
          // flash-native K: rho64 row permute + XOR granule swizzle
          const int s6 = tg & 63;
          const int s5 = s6 & 31, h32 = s6 >> 5;
          const int kh2 = (s5 >> 2) & 1;
          const int gs = ((s5 >> 3) ^ (kh2 << 1)) & 3;
          const int p = h32 * 32 + kh2 * 16 + gs * 4 + (s5 & 3);
          const int gl = ot * 2 + (g >> 1);
          const int gphys = gl ^ (p & 7);
          *(us4*)(kb2 + (size_t)bh * 131072 + (tg >> 6) * 4096 + p * 64 + gphys * 8 + (g & 1) * 4) = pk;
        }
      }
    }
  }

  // V: C = X * W^T (t x o); flash-native sigma-composed store
  {
    const unsigned short* wsrc2 = wvb + (size_t)h * 4096;
    #pragma unroll
    for (int rt = 0; rt < 2; ++rt) {
      bf16x8 a0 = *(const bf16x8*)&Xl[tl0 + rt * 16 + lo][g * 8];
      bf16x8 a1 = *(const bf16x8*)&Xl[tl0 + rt * 16 + lo][32 + g * 8];
      #pragma unroll
      for (int ct = 0; ct < 4; ++ct) {
        bf16x8 b0 = *(const bf16x8*)(wsrc2 + (ct * 16 + lo) * 64 + g * 8);
        bf16x8 b1 = *(const bf16x8*)(wsrc2 + (ct * 16 + lo) * 64 + 32 + g * 8);
        f32x4 acc = {0.f, 0.f, 0.f, 0.f};
        acc = mfma16(a0, b0, acc);
        acc = mfma16(a1, b1, acc);
        const int d = ct * 16 + lo;
        float bvs = bv[h * 64 + d];
        const int tg = t0 + tl0 + rt * 16 + g * 4;
        us4 pk;
        #pragma unroll
        for (int r = 0; r < 4; ++r) pk[r] = f2b(acc[r] + bvs);
        const int lg = (tg & 63) >> 3;
        const int nib = g & 1;
        const int sgi2 = nib ? (lg ^ 2) : lg;
        const int pv = sgi2 ^ (d & 7);
        *(us4*)(vt2 + (size_t)bh * 131072 + (tg >> 6) * 4096 + d * 64 + pv * 8 + nib * 4) = pk;
      }
    }
  }
}

// ---------------- causal flash attention ----------------
// grid: (B*H=32, 32), block 128 = 2 waves x 32 q-rows (2 cols/lane), 64-row tile,
// qt = 31-y (heavy first, r10-proven schedule; 1024 blocks -> backfill depth).
// K/V staged via global_load_lds from flash-native kb2/vt2 (linear coalesced
// copy, zero staging VGPR/VALU); barrier drains vmcnt. Per block-step LDS
// traffic = 48KB vs r10's 80KB. Deferred PV; P in registers; ones-MFMA l.
__launch_bounds__(128)
__global__ void flash_kernel(const unsigned short* __restrict__ q,
                             const unsigned short* __restrict__ kb2,
                             const unsigned short* __restrict__ vt2,
                             unsigned short* __restrict__ ao)
{
  const int bh = blockIdx.x;
  const int b = bh >> 4, h = bh & 15;
  const int qt = 31 - blockIdx.y;
  const int t0 = qt * 64;
  __shared__ unsigned short Kl[2][64][64];
  __shared__ unsigned short Vl[3][64][64];
  const int tid = threadIdx.x, w = tid >> 6, lane = tid & 63, lo = lane & 15, g = lane >> 4;
  const int rs = lo & 7;

  const char* ksrc = (const char*)kb2 + (size_t)bh * 262144;
  const char* vsrc = (const char*)vt2 + (size_t)bh * 262144;
  const int loff = w * 4096 + lane * 16;
  const int wbase = w * 4096;

  const int tw = t0 + w * 32;

  bf16x8 qf[2][2];
  #pragma unroll
  for (int tt = 0; tt < 2; ++tt) {
    const unsigned short* qb = q + ((size_t)(bh * T_ + tw + tt * 16 + lo)) * 64;
    #pragma unroll
    for (int kd = 0; kd < 2; ++kd)
      qf[tt][kd] = *(const bf16x8*)(qb + kd * 32 + g * 8);
  }

  // de-permuted s offsets: sacc[ss][tt][r] has s = s0 + (ss>>1)*32 + sb + r
  const int sb0 = g * 8, sb1 = ((g ^ 2) * 8) + 4;

  union { unsigned u[4]; bf16x8 v; } onec;
  onec.u[0] = onec.u[1] = onec.u[2] = onec.u[3] = 0x3f803f80u;
  const bf16x8 onesv = onec.v;

  float m_[2] = {-1e30f, -1e30f};
  f32x4 zero4 = {0.f, 0.f, 0.f, 0.f};
  f32x4 lacc[2] = {zero4, zero4};
  f32x4 oacc[4][2];
  #pragma unroll
  for (int dt = 0; dt < 4; ++dt)
    #pragma unroll
    for (int tt = 0; tt < 2; ++tt) oacc[dt][tt] = zero4;

  const int nsteps = qt + 1;
  // prologue: DMA step 0 into buffers 0
  {
    const char* ks = ksrc + loff;
    const char* vs = vsrc + loff;
    char* kd = (char*)&Kl[0][0][0] + wbase;
    char* vd = (char*)&Vl[0][0][0] + wbase;
    gl16(ks, kd); gl16(ks + 1024, kd + 1024);
    gl16(ks + 2048, kd + 2048); gl16(ks + 3072, kd + 3072);
    gl16(vs, vd); gl16(vs + 1024, vd + 1024);
    gl16(vs + 2048, vd + 2048); gl16(vs + 3072, vd + 3072);
  }
  __syncthreads();

  bf16x8 pb[2][2];  // previous step's P fragments [tt][kh]
  int vprev = 0;

  for (int stp = 0; stp < nsteps; ++stp) {
    const int cur = stp & 1;
    const int s0 = stp * 64;
    if (stp + 1 < nsteps) {  // DMA next tile (overlaps compute; drained at barrier)
      const char* ks = ksrc + (size_t)(stp + 1) * 8192 + loff;
      const char* vs = vsrc + (size_t)(stp + 1) * 8192 + loff;
      char* kd = (char*)&Kl[cur ^ 1][0][0] + wbase;
      char* vd = (char*)&Vl[(stp + 1) % 3][0][0] + wbase;
      gl16(ks, kd); gl16(ks + 1024, kd + 1024);
      gl16(ks + 2048, kd + 2048); gl16(ks + 3072, kd + 3072);
      gl16(vs, vd); gl16(vs + 1024, vd + 1024);
      gl16(vs + 2048, vd + 2048); gl16(vs + 3072, vd + 3072);
    }
    // ---- MFMA cluster: QK^T(stp) + PV(stp-1) ----
    f32x4 sacc[4][2];
    #pragma unroll
    for (int ss = 0; ss < 4; ++ss)
      #pragma unroll
      for (int tt = 0; tt < 2; ++tt) sacc[ss][tt] = zero4;
    __builtin_amdgcn_s_setprio(1);
    #pragma unroll
    for (int ss = 0; ss < 4; ++ss) {
      bf16x8 ka0 = *(const bf16x8*)&Kl[cur][ss * 16 + lo][(g ^ rs) * 8];
      bf16x8 ka1 = *(const bf16x8*)&Kl[cur][ss * 16 + lo][((g | 4) ^ rs) * 8];
      #pragma unroll
      for (int tt = 0; tt < 2; ++tt) {
        sacc[ss][tt] = mfma16(ka0, qf[tt][0], sacc[ss][tt]);
        sacc[ss][tt] = mfma16(ka1, qf[tt][1], sacc[ss][tt]);
      }
    }
    if (stp > 0) {
      #pragma unroll
      for (int kh = 0; kh < 2; ++kh) {
        #pragma unroll
        for (int dt = 0; dt < 4; ++dt) {
          bf16x8 va = *(const bf16x8*)&Vl[vprev][dt * 16 + lo][((kh * 4 + g) ^ rs) * 8];
          #pragma unroll
          for (int tt = 0; tt < 2; ++tt)
            oacc[dt][tt] = mfma16(va, pb[tt][kh], oacc[dt][tt]);
        }
      }
    }
    __builtin_amdgcn_s_setprio(0);
    // ---- softmax(stp) ----
    if (s0 + 63 > tw) {  // diagonal step: causal mask (de-permuted s)
      #pragma unroll
      for (int ss = 0; ss < 4; ++ss) {
        const int sb = s0 + ((ss & 1) ? sb1 : sb0) + (ss >> 1) * 32;
        #pragma unroll
        for (int tt = 0; tt < 2; ++tt) {
          const int tg = tw + tt * 16 + lo;
          #pragma unroll
          for (int r = 0; r < 4; ++r) {
            if (sb + r > tg) sacc[ss][tt][r] = -1e30f;
          }
        }
      }
    }
    float mx[2];
    #pragma unroll
    for (int tt = 0; tt < 2; ++tt) {
      float a = fmaxf(fmaxf(sacc[0][tt][0], sacc[0][tt][1]), fmaxf(sacc[0][tt][2], sacc[0][tt][3]));
      float b2 = fmaxf(fmaxf(sacc[1][tt][0], sacc[1][tt][1]), fmaxf(sacc[1][tt][2], sacc[1][tt][3]));
      float c = fmaxf(fmaxf(sacc[2][tt][0], sacc[2][tt][1]), fmaxf(sacc[2][tt][2], sacc[2][tt][3]));
      float d = fmaxf(fmaxf(sacc[3][tt][0], sacc[3][tt][1]), fmaxf(sacc[3][tt][2], sacc[3][tt][3]));
      mx[tt] = fmaxf(fmaxf(a, b2), fmaxf(c, d));
    }
    if (!__all((mx[0] <= m_[0] + 8.0f) && (mx[1] <= m_[1] + 8.0f))) {  // rare rescale
      #pragma unroll
      for (int tt = 0; tt < 2; ++tt) {
        float mv = mx[tt];
        mv = fmaxf(mv, __shfl_xor(mv, 16));
        mv = fmaxf(mv, __shfl_xor(mv, 32));
        float mn = fmaxf(m_[tt], mv);
        float corr = fexp2(m_[tt] - mn);
        m_[tt] = mn;
        lacc[tt] *= corr;
        #pragma unroll
        for (int dt = 0; dt < 4; ++dt) oacc[dt][tt] *= corr;
      }
    }
    // exp2 + pack: pb directly from own values (sigma-aligned V)
    #pragma unroll
    for (int tt = 0; tt < 2; ++tt) {
      #pragma unroll
      for (int kh = 0; kh < 2; ++kh) {
        union { unsigned u[4]; bf16x8 v; } pbc;
        #pragma unroll
        for (int half2 = 0; half2 < 2; ++half2) {
          const int ss = kh * 2 + half2;
          float p0 = fexp2(sacc[ss][tt][0] - m_[tt]);
          float p1 = fexp2(sacc[ss][tt][1] - m_[tt]);
          float p2 = fexp2(sacc[ss][tt][2] - m_[tt]);
          float p3 = fexp2(sacc[ss][tt][3] - m_[tt]);
          pbc.u[half2 * 2]     = pkw(p0, p1);
          pbc.u[half2 * 2 + 1] = pkw(p2, p3);
        }
        pb[tt][kh] = pbc.v;
        lacc[tt] = mfma16(onesv, pb[tt][kh], lacc[tt]);
      }
    }
    vprev = stp % 3;
    __syncthreads();  // drains gl16 (vmcnt) + protects buffer swap
  }
  // epilogue: drain PV(last)
  __builtin_amdgcn_s_setprio(1);
  #pragma unroll
  for (int kh = 0; kh < 2; ++kh) {
    #pragma unroll
    for (int dt = 0; dt < 4; ++dt) {
      bf16x8 va = *(const bf16x8*)&Vl[vprev][dt * 16 + lo][((kh * 4 + g) ^ rs) * 8];
      #pragma unroll
      for (int tt = 0; tt < 2; ++tt)
        oacc[dt][tt] = mfma16(va, pb[tt][kh], oacc[dt][tt]);
    }
  }
  __builtin_amdgcn_s_setprio(0);
  #pragma unroll
  for (int tt = 0; tt < 2; ++tt) {
    float inv = 1.0f / lacc[tt][0];
    unsigned short* op = ao + ((size_t)(b * T_ + tw + tt * 16 + lo)) * E_ + h * 64;
    #pragma unroll
    for (int dt = 0; dt < 4; ++dt) {
      us4 pk;
      #pragma unroll
      for (int r = 0; r < 4; ++r) pk[r] = f2b(oacc[dt][tt][r] * inv);
      *(us4*)(op + dt * 16 + g * 4) = pk;
    }
  }
}

// ---------------- output projection (r14, BK=64, XCD-partitioned) ----------------
__launch_bounds__(256)
__global__ void proj_kernel(const unsigned short* __restrict__ ao,
                            const unsigned short* __restrict__ wpb,
                            const float* __restrict__ bp,
                            float* __restrict__ out)
{
  const int bid = blockIdx.x;
  const int xcd = bid & 7, idx = bid >> 3;
  const int m0 = (xcd * 4 + (idx & 3)) * 128;
  const int n0 = (idx >> 2) * 64;
  __shared__ unsigned short Al[2][128][72];
  __shared__ unsigned short Bl[2][64][72];
  const int tid = threadIdx.x, w = tid >> 6, lane = tid & 63, lo = lane & 15, g = lane >> 4;
  const int wr = (w >> 1) * 64, wc = (w & 1) * 32;
  f32x4 zero4 = {0.f, 0.f, 0.f, 0.f};
  f32x4 acc[4][2];
  #pragma unroll
  for (int i = 0; i < 4; ++i)
    #pragma unroll
    for (int j = 0; j < 2; ++j) acc[i][j] = zero4;

  const int arow = tid >> 1, acol = (tid & 1) * 32;
  const int brow = tid >> 2, bcol = (tid & 3) * 16;
  const unsigned short* abase = ao + (size_t)(m0 + arow) * 1024 + acol;
  const unsigned short* bbase = wpb + (size_t)(n0 + brow) * 1024 + bcol;

  us8 a0, a1, a2, a3, b0, b1;
  a0 = *(const us8*)(abase);
  a1 = *(const us8*)(abase + 8);
  a2 = *(const us8*)(abase + 16);
  a3 = *(const us8*)(abase + 24);
  b0 = *(const us8*)(bbase);
  b1 = *(const us8*)(bbase + 8);
  *(us8*)&Al[0][arow][acol] = a0;
  *(us8*)&Al[0][arow][acol + 8] = a1;
  *(us8*)&Al[0][arow][acol + 16] = a2;
  *(us8*)&Al[0][arow][acol + 24] = a3;
  *(us8*)&Bl[0][brow][bcol] = b0;
  *(us8*)&Bl[0][brow][bcol + 8] = b1;
  a0 = *(const us8*)(abase + 64);
  a1 = *(const us8*)(abase + 72);
  a2 = *(const us8*)(abase + 80);
  a3 = *(const us8*)(abase + 88);
  b0 = *(const us8*)(bbase + 64);
  b1 = *(const us8*)(bbase + 72);
  __syncthreads();

  for (int it = 0; it < 16; ++it) {
    const int cur = it & 1;
    us8 na0, na1, na2, na3, nb0, nb1;
    const bool pf = (it + 2 < 16);
    if (pf) {
      const int kn = (it + 2) * 64;
      na0 = *(const us8*)(abase + kn);
      na1 = *(const us8*)(abase + kn + 8);
      na2 = *(const us8*)(abase + kn + 16);
      na3 = *(const us8*)(abase + kn + 24);
      nb0 = *(const us8*)(bbase + kn);
      nb1 = *(const us8*)(bbase + kn + 8);
    }
    bf16x8 af[4][2], bfr[2][2];
    #pragma unroll
    for (int kk = 0; kk < 2; ++kk) {
      #pragma unroll
      for (int i = 0; i < 4; ++i)
        af[i][kk] = *(const bf16x8*)&Al[cur][wr + i * 16 + lo][kk * 32 + g * 8];
      #pragma unroll
      for (int j = 0; j < 2; ++j)
        bfr[j][kk] = *(const bf16x8*)&Bl[cur][wc + j * 16 + lo][kk * 32 + g * 8];
    }
    __builtin_amdgcn_s_setprio(1);
    #pragma unroll
    for (int kk = 0; kk < 2; ++kk)
      #pragma unroll
      for (int i = 0; i < 4; ++i)
        #pragma unroll
        for (int j = 0; j < 2; ++j)
          acc[i][j] = mfma16(af[i][kk], bfr[j][kk], acc[i][j]);
    __builtin_amdgcn_s_setprio(0);
    if (it + 1 < 16) {
      *(us8*)&Al[cur ^ 1][arow][acol] = a0;
      *(us8*)&Al[cur ^ 1][arow][acol + 8] = a1;
      *(us8*)&Al[cur ^ 1][arow][acol + 16] = a2;
      *(us8*)&Al[cur ^ 1][arow][acol + 24] = a3;
      *(us8*)&Bl[cur ^ 1][brow][bcol] = b0;
      *(us8*)&Bl[cur ^ 1][brow][bcol + 8] = b1;
    }
    __syncthreads();
    if (pf) { a0 = na0; a1 = na1; a2 = na2; a3 = na3; b0 = nb0; b1 = nb1; }
  }
  #pragma unroll
  for (int j = 0; j < 2; ++j) {
    int n = n0 + wc + j * 16 + lo;
    float bias = bp[n];
    #pragma unroll
    for (int i = 0; i < 4; ++i) {
      #pragma unroll
      for (int r = 0; r < 4; ++r)
        out[(size_t)(m0 + wr + i * 16 + g * 4 + r) * 1024 + n] = acc[i][j][r] + bias;
    }
  }
}

extern "C" void kernel_launch(void* const* d_in, const int* in_sizes, int n_in,
                              void* d_out, int out_size, void* d_ws, size_t ws_size,
                              hipStream_t stream)
{
  const float* x  = (const float*)d_in[0];
  const float* Wq = (const float*)d_in[2];
  const float* bq = (const float*)d_in[3];
  const float* Wk = (const float*)d_in[4];
  const float* bk = (const float*)d_in[5];
  const float* Wv = (const float*)d_in[6];
  const float* bv = (const float*)d_in[7];
  const float* Wp = (const float*)d_in[8];
  const float* bp = (const float*)d_in[9];
  float* out = (float*)d_out;

  char* ws = (char*)d_ws;
  const size_t SZ = (size_t)2 * 16 * 2048 * 64 * 2;  // 8 MB per bf16 tensor
  unsigned short* q   = (unsigned short*)(ws);
  unsigned short* kb2 = (unsigned short*)(ws + SZ);
  unsigned short* vt2 = (unsigned short*)(ws + 2 * SZ);
  unsigned short* ao  = (unsigned short*)(ws + 3 * SZ);
  unsigned short* wpb = (unsigned short*)(ws + 4 * SZ);            // 2 MB
  unsigned short* wqb = (unsigned short*)(ws + 4 * SZ + 2097152);  // 128 KB each
  unsigned short* wkb = wqb + 65536;
  unsigned short* wvb = wqb + 131072;

  cvt_kernel<<<dim3(1216), 256, 0, stream>>>(Wq, Wk, Wv, Wp, wqb, wkb, wvb, wpb);
  qkv_kernel<<<dim3(32, 16), 256, 0, stream>>>(x, wqb, bq, wkb, bk, wvb, bv, q, kb2, vt2);
  flash_kernel<<<dim3(32, 32), 128, 0, stream>>>(q, kb2, vt2, ao);
  proj_kernel<<<dim3(512), 256, 0, stream>>>(ao, wpb, bp, out);
}